// Round 4
// baseline (613.312 us; speedup 1.0000x reference)
//
#include <hip/hip_runtime.h>

// VQ-VAE vector quantization forward — MFMA fast-path + exact np recheck.
// x: [32,64,64,64] f32 -> flat [N=131072, D=64]; embeddings: [D=64, K=512].
//
// Exactness contract: chosen index per row == np argmin over
// dist_k = fl(fl(A+B_k) - fl(2*sim_k)), first-min tie. Fast path computes a
// biased proxy s' = (B_k+32) - 2*sim_split (A row-constant, dropped) and
// flags any row whose proxy min-gap <= THRESH_FAST for exact np rescan.
// Error budget (split-product ~7.5e-5 + lo*lo drop ~3e-5 + 5-bit mantissa
// packing ~1.2e-4 + bias rounding ~2e-6 + f32 accum ~1e-5 => E ~ 2.4e-4):
// wrong argmin => measured gap <= 4E = 9.6e-4 < THRESH_FAST=1.5e-3 =>
// flagged. Unflagged => argmin == np. out/loss np-exact everywhere.
//
// Round 14 — r13 books: main 62us but TOTAL 188. Cross-round closure shows
// vq_fix has been ~60-75us hiding JUST under the top-5 cutoff (=main's dur)
// since r11 — the top-5 table is censored at the 5th-largest dispatch.
//  - FUSION: main + done-barrier + fix + finalize in ONE kernel (1024
//    blocks, provably co-resident: bounds(256,4), VGPR<=128, LDS ~5KB =>
//    4 blk/CU x 256 CU). Kills 2 graph nodes + gaps; fix phase now INSIDE
//    the top dispatch => next counters can't hide it. Device-scope
//    release/acquire around the barrier (Guideline 16).
//  - main K-loop / epilogue / flag logic: byte-identical to r13 (62us).
//  - fix compute: r12's validated np-exact 4-rows/wave batch; 4096 waves
//    cover SLOWCAP in one batch each.
// vq_prep: r13 body + resets cnt[0..2] (graph edge gives table visibility).

constexpr int D = 64;
constexpr int K = 512;
constexpr int NROWS = 131072;
constexpr long long NELEM = 8388608LL;
constexpr int RPB = 128;     // rows per block (2 row-tiles per wave)
constexpr float THRESH_FAST = 1.5e-3f;
constexpr int SLOWCAP = 16384;
constexpr float BIAS = 32.0f;  // |2*sim| < 10 for this data => s' in [22,42]

typedef __attribute__((ext_vector_type(8))) short bf16x8;
typedef __attribute__((ext_vector_type(4))) float f32x4;

__device__ __forceinline__ unsigned short bf16_rne(float f) {
    unsigned int u = __float_as_uint(f);
    unsigned int r = u + 0x7fffu + ((u >> 16) & 1u);
    return (unsigned short)(r >> 16);
}
__device__ __forceinline__ float bf16_f(unsigned short h) {
    return __uint_as_float(((unsigned int)h) << 16);
}
__device__ __forceinline__ unsigned int umin32(unsigned int a, unsigned int b) {
    return a < b ? a : b;
}
__device__ __forceinline__ unsigned int umax32(unsigned int a, unsigned int b) {
    return a > b ? a : b;
}

// ws map (float offsets): 0 loss | 1..3 cnt[3] (flags, main_done, fix_done)
// | 64 e2[512] | 1024 ebf (128KB) | 33792 embT[512*64] | 66560 slow[16384].

// Prep: 32 blocks x 256. Block b owns ebf tile b = codes [b*16, b*16+16).
__global__ __launch_bounds__(256) void vq_prep(const float* __restrict__ emb,
                                               float* __restrict__ e2,
                                               unsigned short* __restrict__ ebf,
                                               float* __restrict__ embT,
                                               float* __restrict__ loss_acc,
                                               int* __restrict__ cnt) {
    const int tid = threadIdx.x;
    const int b = blockIdx.x;
    const int c0 = b * 16;
    __shared__ float se[64][17];  // se[d][cl], padded

    // Stage 64 d x 16 codes (64B segments, 4 independent loads/thread).
#pragma unroll
    for (int it = 0; it < 4; ++it) {
        const int idx = it * 256 + tid;   // 0..1023
        const int d = idx >> 4, cl = idx & 15;
        se[d][cl] = emb[d * K + c0 + cl];
    }
    __syncthreads();

    // e2: np axis-0 sequential order (identical rounding chain).
    if (tid < 16) {
        const int cl = tid;
        float bacc = __fmul_rn(se[0][cl], se[0][cl]);
#pragma unroll
        for (int d = 1; d < 64; ++d)
            bacc = __fadd_rn(bacc, __fmul_rn(se[d][cl], se[d][cl]));
        e2[c0 + cl] = bacc;
    }

    // embT[c][d]: 256 float4, one per thread.
    {
        const int cl = tid >> 4;
        const int d0 = (tid & 15) * 4;
        float4 v;
        v.x = se[d0 + 0][cl];
        v.y = se[d0 + 1][cl];
        v.z = se[d0 + 2][cl];
        v.w = se[d0 + 3][cl];
        *reinterpret_cast<float4*>(embT + (size_t)(c0 + cl) * D + d0) = v;
    }

    // ebf tile b: 256 uint4, one per thread. Layout (r9-identical):
    // tile*2048 + table*1024 + half*512 + lane*8 + j,
    // value = split_table( e[d = q*8+j+32*half][c = tile*16 + (lane&15)] ).
    {
        const int table = tid >> 7;
        const int half = (tid >> 6) & 1;
        const int lane = tid & 63;
        const int q = lane >> 4, mm = lane & 15;
        unsigned short v[8];
#pragma unroll
        for (int j = 0; j < 8; ++j) {
            const float e = se[q * 8 + j + 32 * half][mm];
            unsigned short h1 = bf16_rne(e);
            v[j] = table ? bf16_rne(e - bf16_f(h1)) : h1;
        }
        *reinterpret_cast<uint4*>(ebf + (size_t)b * 2048 + table * 1024 +
                                  half * 512 + lane * 8) =
            *reinterpret_cast<const uint4*>(&v[0]);
    }

    if (b == 0 && tid == 0) {
        loss_acc[0] = 0.f;
        cnt[0] = 0; cnt[1] = 0; cnt[2] = 0;
    }
}

// Fused: MFMA argmin main (r13-identical) -> device barrier -> exact np fix
// (r12-identical compute) -> finalize. 1024 blocks co-resident by
// construction (bounds(256,4), VGPR<=128, LDS ~5KB => 4 blocks/CU).
__global__ __launch_bounds__(256, 4) void vq_fused(
    const float* __restrict__ x, const float* __restrict__ emb,
    const float* __restrict__ e2g, const unsigned short* __restrict__ ebf,
    const float* __restrict__ embT, float* __restrict__ out,
    float* __restrict__ loss_acc, int* __restrict__ slow,
    int* __restrict__ cnt) {
    const int tid = threadIdx.x;
    const int l = tid & 63;
    const int wv = tid >> 6;
    const int m = l & 15, q = l >> 4;

    __shared__ int bxl[RPB];
    __shared__ float wsum[4];

    // ---------------- Phase 1: main (byte-identical to r13) ----------------
    const unsigned short* tb0 = ebf + l * 8;
    bf16x8 c10 = *reinterpret_cast<const bf16x8*>(tb0);
    bf16x8 c11 = *reinterpret_cast<const bf16x8*>(tb0 + 512);
    bf16x8 c20 = *reinterpret_cast<const bf16x8*>(tb0 + 1024);
    bf16x8 c21 = *reinterpret_cast<const bf16x8*>(tb0 + 1536);
    float BnC = e2g[m] + BIAS;

    bf16x8 a10[2], a11[2], a20[2], a21[2];
#pragma unroll
    for (int rt = 0; rt < 2; ++rt) {
        const float* xr =
            x + ((size_t)blockIdx.x * RPB + wv * 32 + rt * 16 + m) * D + q * 8;
        float4 v0 = *reinterpret_cast<const float4*>(xr);
        float4 v1 = *reinterpret_cast<const float4*>(xr + 4);
        float4 v2 = *reinterpret_cast<const float4*>(xr + 32);
        float4 v3 = *reinterpret_cast<const float4*>(xr + 36);
        float h0[8] = {v0.x, v0.y, v0.z, v0.w, v1.x, v1.y, v1.z, v1.w};
        float h1f[8] = {v2.x, v2.y, v2.z, v2.w, v3.x, v3.y, v3.z, v3.w};
        union { bf16x8 v; unsigned short u[8]; } u10, u11, u20, u21;
#pragma unroll
        for (int j = 0; j < 8; ++j) {
            unsigned short p = bf16_rne(h0[j]), r = bf16_rne(h1f[j]);
            u10.u[j] = p; u11.u[j] = r;
            u20.u[j] = bf16_rne(h0[j] - bf16_f(p));
            u21.u[j] = bf16_rne(h1f[j] - bf16_f(r));
        }
        a10[rt] = u10.v; a11[rt] = u11.v; a20[rt] = u20.v; a21[rt] = u21.v;
    }

    unsigned int m1p[2][4], m2p[2][4];
#pragma unroll
    for (int rt = 0; rt < 2; ++rt)
#pragma unroll
        for (int g = 0; g < 4; ++g) { m1p[rt][g] = 0xFFFFFFFFu; m2p[rt][g] = 0xFFFFFFFFu; }

#pragma unroll 2
    for (int t = 0; t < 32; ++t) {
        const unsigned short* nb = ebf + (((t + 1) & 31) * 2048) + l * 8;
        bf16x8 n10 = *reinterpret_cast<const bf16x8*>(nb);
        bf16x8 n11 = *reinterpret_cast<const bf16x8*>(nb + 512);
        bf16x8 n20 = *reinterpret_cast<const bf16x8*>(nb + 1024);
        bf16x8 n21 = *reinterpret_cast<const bf16x8*>(nb + 1536);
        float BnN = e2g[(((t + 1) & 31) << 4) + m] + BIAS;

        f32x4 cp[2], cq[2];
#pragma unroll
        for (int rt = 0; rt < 2; ++rt) {
            cp[rt] = f32x4{0.f, 0.f, 0.f, 0.f};
            cq[rt] = f32x4{0.f, 0.f, 0.f, 0.f};
        }
#pragma unroll
        for (int rt = 0; rt < 2; ++rt) {
            cp[rt] = __builtin_amdgcn_mfma_f32_16x16x32_bf16(a10[rt], c10, cp[rt], 0, 0, 0);
            cq[rt] = __builtin_amdgcn_mfma_f32_16x16x32_bf16(a20[rt], c10, cq[rt], 0, 0, 0);
            cp[rt] = __builtin_amdgcn_mfma_f32_16x16x32_bf16(a11[rt], c11, cp[rt], 0, 0, 0);
            cq[rt] = __builtin_amdgcn_mfma_f32_16x16x32_bf16(a21[rt], c11, cq[rt], 0, 0, 0);
            cq[rt] = __builtin_amdgcn_mfma_f32_16x16x32_bf16(a10[rt], c20, cq[rt], 0, 0, 0);
            cq[rt] = __builtin_amdgcn_mfma_f32_16x16x32_bf16(a11[rt], c21, cq[rt], 0, 0, 0);
        }
#pragma unroll
        for (int rt = 0; rt < 2; ++rt)
#pragma unroll
            for (int g = 0; g < 4; ++g) {
                float s = fmaf(-2.f, cp[rt][g] + cq[rt][g], BnC);
                unsigned int pi =
                    (__float_as_uint(s) & 0xFFFFFFE0u) | (unsigned int)t;
                unsigned int o1 = m1p[rt][g];
                m2p[rt][g] = umin32(umax32(pi, o1), m2p[rt][g]);
                m1p[rt][g] = umin32(o1, pi);
            }
        c10 = n10; c11 = n11; c20 = n20; c21 = n21; BnC = BnN;
    }

#pragma unroll
    for (int rt = 0; rt < 2; ++rt)
#pragma unroll
        for (int g = 0; g < 4; ++g) {
            unsigned int uv = m1p[rt][g] & 0xFFFFFFE0u;
            int col = (int)((m1p[rt][g] & 31u) << 4) | m;
            unsigned int m2v = m2p[rt][g] & 0xFFFFFFE0u;
#pragma unroll
            for (int off = 1; off < 16; off <<= 1) {
                unsigned int ouv = (unsigned int)__shfl_xor((int)uv, off, 64);
                int ocol = __shfl_xor(col, off, 64);
                unsigned int om2 = (unsigned int)__shfl_xor((int)m2v, off, 64);
                unsigned int nm2 = umin32(umax32(uv, ouv), umin32(m2v, om2));
                bool take = (ouv < uv) || (ouv == uv && ocol < col);
                if (take) { uv = ouv; col = ocol; }
                m2v = nm2;  // equal mins, diff idx -> gap 0 -> slow
            }
            if (m == 0) {
                const int rl = wv * 32 + rt * 16 + q * 4 + g;  // row in block
                bxl[rl] = col;
                float gap = __uint_as_float(m2v) - __uint_as_float(uv);
                if (!(gap > THRESH_FAST)) {
                    int p = atomicAdd(cnt, 1);
                    if (p < SLOWCAP)
                        slow[p] = ((blockIdx.x * RPB + rl) << 9) | col;
                }
            }
        }
    __syncthreads();

    // Fused epilogue (r6-validated numerics, embT contiguous gather).
    float lsum = 0.f;
#pragma unroll
    for (int j = 0; j < 8; ++j) {
        const int e4 = j * 256 + tid;
        const int rr2 = e4 >> 4;
        const int d0 = (e4 & 15) * 4;
        const size_t gbase = (size_t)(blockIdx.x * RPB + rr2) * D + d0;
        const float4 xv = *reinterpret_cast<const float4*>(x + gbase);
        const float4 qv =
            *reinterpret_cast<const float4*>(embT + bxl[rr2] * D + d0);
        float4 o;
        float t;
        t = __fsub_rn(qv.x, xv.x); lsum = __fmaf_rn(t, t, lsum);
        o.x = __fadd_rn(xv.x, t);
        t = __fsub_rn(qv.y, xv.y); lsum = __fmaf_rn(t, t, lsum);
        o.y = __fadd_rn(xv.y, t);
        t = __fsub_rn(qv.z, xv.z); lsum = __fmaf_rn(t, t, lsum);
        o.z = __fadd_rn(xv.z, t);
        t = __fsub_rn(qv.w, xv.w); lsum = __fmaf_rn(t, t, lsum);
        o.w = __fadd_rn(xv.w, t);
        *reinterpret_cast<float4*>(out + gbase) = o;
    }
#pragma unroll
    for (int off = 32; off > 0; off >>= 1) lsum += __shfl_down(lsum, off, 64);
    if (l == 0) wsum[wv] = lsum;
    __syncthreads();
    if (tid == 0)
        atomicAdd(loss_acc, wsum[0] + wsum[1] + wsum[2] + wsum[3]);

    // ------------- Device barrier: all blocks done with phase 1 -------------
    // All 1024 blocks are co-resident (4/CU by launch bounds + resources),
    // so arrive-and-spin cannot deadlock. Release: threadfence + ACQ_REL add.
    __threadfence();
    if (tid == 0) {
        __hip_atomic_fetch_add(&cnt[1], 1, __ATOMIC_ACQ_REL,
                               __HIP_MEMORY_SCOPE_AGENT);
        while (__hip_atomic_load(&cnt[1], __ATOMIC_ACQUIRE,
                                 __HIP_MEMORY_SCOPE_AGENT) < (int)gridDim.x)
            __builtin_amdgcn_s_sleep(2);
    }
    __syncthreads();

    // ---------------- Phase 2: exact np fix (r12 compute) ----------------
    int n = __hip_atomic_load(&cnt[0], __ATOMIC_RELAXED,
                              __HIP_MEMORY_SCOPE_AGENT);
    if (n > SLOWCAP) n = SLOWCAP;
    const int lane = l;
    const int wg = blockIdx.x * 4 + wv;  // 4096 waves; wg*4+4 <= 16384+12
    const int base = wg * 4;
    if (base < n) {
        const int c4 = (n - base < 4) ? (n - base) : 4;
        int rows[4], fidxs[4];
        float xr[4], A[4];
#pragma unroll
        for (int j = 0; j < 4; ++j) {
            const int src = base + ((j < c4) ? j : 0);  // pad with entry 0
            const int entry = __builtin_amdgcn_readfirstlane(slow[src]);
            rows[j] = entry >> 9;
            fidxs[j] = entry & 511;
            xr[j] = x[(size_t)rows[j] * D + lane];  // whole row in the wave
        }
        // A[j]: np pairwise-8 via distributed xor-tree (bit-exact grouping).
#pragma unroll
        for (int j = 0; j < 4; ++j) {
            const int jj = lane & 7;
            float v = __shfl(xr[j], jj, 64);
            float r8 = __fmul_rn(v, v);
#pragma unroll
            for (int ii = 8; ii < 64; ii += 8) {
                v = __shfl(xr[j], ii + jj, 64);
                r8 = __fadd_rn(r8, __fmul_rn(v, v));
            }
            r8 = __fadd_rn(r8, __shfl_xor(r8, 1, 64));
            r8 = __fadd_rn(r8, __shfl_xor(r8, 2, 64));
            r8 = __fadd_rn(r8, __shfl_xor(r8, 4, 64));
            A[j] = r8;
        }
        // Shared sim phase: one 2KB ev slice feeds 4 rows; xd via shuffle.
        float acc[4][8];
#pragma unroll
        for (int j = 0; j < 4; ++j)
#pragma unroll
            for (int u = 0; u < 8; ++u) acc[j][u] = 0.f;
#pragma unroll 4
        for (int d = 0; d < D; ++d) {
            float ev[8];
#pragma unroll
            for (int u = 0; u < 8; ++u) ev[u] = emb[d * K + lane + 64 * u];
#pragma unroll
            for (int j = 0; j < 4; ++j) {
                const float xd = __shfl(xr[j], d, 64);
#pragma unroll
                for (int u = 0; u < 8; ++u)
                    acc[j][u] = __fmaf_rn(xd, ev[u], acc[j][u]);
            }
        }
        float e2v[8];
#pragma unroll
        for (int u = 0; u < 8; ++u) e2v[u] = e2g[lane + 64 * u];
        // Per-row argmin + rewrite + loss delta (r9-identical chains).
#pragma unroll
        for (int j = 0; j < 4; ++j)
            if (j < c4) {
                const int row = rows[j];
                const int fidx = fidxs[j];
                float bv = 3.0e38f;
                int bi = 0;
#pragma unroll
                for (int u = 0; u < 8; ++u) {
                    const int c = lane + 64 * u;
                    float dv = __fsub_rn(__fadd_rn(A[j], e2v[u]),
                                         __fmul_rn(2.f, acc[j][u]));
                    if (dv < bv) { bv = dv; bi = c; }  // ascending c in lane
                }
#pragma unroll
                for (int off = 1; off < 64; off <<= 1) {
                    float ov = __shfl_xor(bv, off, 64);
                    int oi = __shfl_xor(bi, off, 64);
                    if (ov < bv || (ov == bv && oi < bi)) { bv = ov; bi = oi; }
                }
                float part = 0.f;
                if (lane < 16) {
                    const int d0 = lane * 4;
                    const float4 xv = *reinterpret_cast<const float4*>(
                        x + (size_t)row * D + d0);
                    const float4 qo = *reinterpret_cast<const float4*>(
                        embT + fidx * D + d0);
                    const float4 qn = *reinterpret_cast<const float4*>(
                        embT + bi * D + d0);
                    float so = 0.f, sn = 0.f, t;
                    float4 o;
                    t = __fsub_rn(qo.x, xv.x); so = __fmaf_rn(t, t, so);
                    t = __fsub_rn(qo.y, xv.y); so = __fmaf_rn(t, t, so);
                    t = __fsub_rn(qo.z, xv.z); so = __fmaf_rn(t, t, so);
                    t = __fsub_rn(qo.w, xv.w); so = __fmaf_rn(t, t, so);
                    t = __fsub_rn(qn.x, xv.x); sn = __fmaf_rn(t, t, sn);
                    o.x = __fadd_rn(xv.x, t);
                    t = __fsub_rn(qn.y, xv.y); sn = __fmaf_rn(t, t, sn);
                    o.y = __fadd_rn(xv.y, t);
                    t = __fsub_rn(qn.z, xv.z); sn = __fmaf_rn(t, t, sn);
                    o.z = __fadd_rn(xv.z, t);
                    t = __fsub_rn(qn.w, xv.w); sn = __fmaf_rn(t, t, sn);
                    o.w = __fadd_rn(xv.w, t);
                    *reinterpret_cast<float4*>(out + (size_t)row * D + d0) = o;
                    part = sn - so;  // exactly 0 when bi == fidx
                }
#pragma unroll
                for (int off = 32; off > 0; off >>= 1)
                    part += __shfl_down(part, off, 64);
                if (lane == 0 && part != 0.f) atomicAdd(loss_acc, part);
            }
    }

    // ---------------- Finalize: last block writes the loss ----------------
    __threadfence();
    if (tid == 0) {
        int dcnt = __hip_atomic_fetch_add(&cnt[2], 1, __ATOMIC_ACQ_REL,
                                          __HIP_MEMORY_SCOPE_AGENT);
        if (dcnt == (int)gridDim.x - 1) {
            float total = atomicAdd(loss_acc, 0.0f);  // device-coherent read
            float mm = total / (float)NELEM;          // /2^23: exact
            out[NELEM] = 1.25f * mm;                  // == fl(0.25m + m)
        }
    }
}

extern "C" void kernel_launch(void* const* d_in, const int* in_sizes, int n_in,
                              void* d_out, int out_size, void* d_ws, size_t ws_size,
                              hipStream_t stream) {
    const float* x = (const float*)d_in[0];
    const float* emb = (const float*)d_in[1];
    float* out = (float*)d_out;

    float* ws = (float*)d_ws;
    float* loss_acc = ws;
    int* cnt = (int*)ws + 1;   // cnt[0]=flags, cnt[1]=main_done, cnt[2]=fix_done
    float* e2 = ws + 64;
    unsigned short* ebf = (unsigned short*)(ws + 1024);  // 128 KB
    float* embT = ws + 33792;                            // 128 KB
    int* slow = (int*)(ws + 66560);                      // 64 KB

    vq_prep<<<32, 256, 0, stream>>>(emb, e2, ebf, embT, loss_acc, cnt);
    vq_fused<<<NROWS / RPB, 256, 0, stream>>>(x, emb, e2, ebf, embT, out,
                                              loss_acc, slow, cnt);
}

// Round 5
// 147.456 us; speedup vs baseline: 4.1593x; 4.1593x over previous
//
#include <hip/hip_runtime.h>

// VQ-VAE vector quantization forward — MFMA fast-path + exact np recheck.
// x: [32,64,64,64] f32 -> flat [N=131072, D=64]; embeddings: [D=64, K=512].
//
// Exactness contract: chosen index per row == np argmin over
// dist_k = fl(fl(A+B_k) - fl(2*sim_k)), first-min tie. Fast path computes a
// biased proxy s' = (B_k+32) - 2*sim_split (A row-constant, dropped) and
// flags any row whose proxy min-gap <= THRESH_FAST for exact np rescan.
// Error budget (split-product ~7.5e-5 + lo*lo drop ~3e-5 + 5-bit mantissa
// packing ~1.2e-4 + bias rounding ~2e-6 + f32 accum ~1e-5 => E ~ 2.4e-4):
// wrong argmin => measured gap <= 4E = 9.6e-4 < THRESH_FAST=1.5e-3 =>
// flagged. Unflagged => argmin == np. out/loss np-exact everywhere.
//
// Round 15 — r14 books: fused spin-barrier = 563us @ MfmaUtil 1.8% —
// device-wide arrive-and-spin costs ~500us on this part. ABANDONED.
// Back to separate kernels (r2 structure, best total 158.8), with main
// redesigned around the one fact that held across r10-r13: main is
// L2-bound on the b-frag stream (each wave re-reads the 128KB table; 4GB
// aggregate), not pipe-bound (MfmaUtil 16%, floors ~12us MFMA / ~10us HBM).
//  - vq_main: 256 blocks x 1024 threads (16 waves), bounds(1024,4) => 1
//    block/CU, 16 waves/CU. ENTIRE ebf table (128KB) staged to LDS once per
//    block (L2 traffic /32); barrier-free K-loop of conflict-free
//    ds_read_b128 + 12 MFMAs/t; packed-u32 argmin (r13-proven). e2 in LDS.
//  - vq_fix / vq_finalize: byte-identical to r12/r2 (best-total round).
//  - vq_prep: unchanged (32 blocks).

constexpr int D = 64;
constexpr int K = 512;
constexpr int NROWS = 131072;
constexpr long long NELEM = 8388608LL;
constexpr int RPB = 512;     // rows per block (16 waves x 2 row-tiles x 16)
constexpr float THRESH_FAST = 1.5e-3f;
constexpr int SLOWCAP = 16384;
constexpr float BIAS = 32.0f;  // |2*sim| < 10 for this data => s' in [22,42]

typedef __attribute__((ext_vector_type(8))) short bf16x8;
typedef __attribute__((ext_vector_type(4))) float f32x4;

__device__ __forceinline__ unsigned short bf16_rne(float f) {
    unsigned int u = __float_as_uint(f);
    unsigned int r = u + 0x7fffu + ((u >> 16) & 1u);
    return (unsigned short)(r >> 16);
}
__device__ __forceinline__ float bf16_f(unsigned short h) {
    return __uint_as_float(((unsigned int)h) << 16);
}
__device__ __forceinline__ unsigned int umin32(unsigned int a, unsigned int b) {
    return a < b ? a : b;
}
__device__ __forceinline__ unsigned int umax32(unsigned int a, unsigned int b) {
    return a > b ? a : b;
}

// ws map (float offsets): 0 loss | 1 cnt | 64 e2[512] | 1024 ebf (128KB)
// | 33792 embT[512*64] | 66560 slow[16384] ints.

// Prep: 32 blocks x 256. Block b owns ebf tile b = codes [b*16, b*16+16).
__global__ __launch_bounds__(256) void vq_prep(const float* __restrict__ emb,
                                               float* __restrict__ e2,
                                               unsigned short* __restrict__ ebf,
                                               float* __restrict__ embT,
                                               float* __restrict__ loss_acc,
                                               int* __restrict__ cnt) {
    const int tid = threadIdx.x;
    const int b = blockIdx.x;
    const int c0 = b * 16;
    __shared__ float se[64][17];  // se[d][cl], padded

    // Stage 64 d x 16 codes (64B segments, 4 independent loads/thread).
#pragma unroll
    for (int it = 0; it < 4; ++it) {
        const int idx = it * 256 + tid;   // 0..1023
        const int d = idx >> 4, cl = idx & 15;
        se[d][cl] = emb[d * K + c0 + cl];
    }
    __syncthreads();

    // e2: np axis-0 sequential order (identical rounding chain).
    if (tid < 16) {
        const int cl = tid;
        float bacc = __fmul_rn(se[0][cl], se[0][cl]);
#pragma unroll
        for (int d = 1; d < 64; ++d)
            bacc = __fadd_rn(bacc, __fmul_rn(se[d][cl], se[d][cl]));
        e2[c0 + cl] = bacc;
    }

    // embT[c][d]: 256 float4, one per thread.
    {
        const int cl = tid >> 4;
        const int d0 = (tid & 15) * 4;
        float4 v;
        v.x = se[d0 + 0][cl];
        v.y = se[d0 + 1][cl];
        v.z = se[d0 + 2][cl];
        v.w = se[d0 + 3][cl];
        *reinterpret_cast<float4*>(embT + (size_t)(c0 + cl) * D + d0) = v;
    }

    // ebf tile b: 256 uint4, one per thread. Layout (r9-identical):
    // tile*2048 + table*1024 + half*512 + lane*8 + j,
    // value = split_table( e[d = q*8+j+32*half][c = tile*16 + (lane&15)] ).
    {
        const int table = tid >> 7;
        const int half = (tid >> 6) & 1;
        const int lane = tid & 63;
        const int q = lane >> 4, mm = lane & 15;
        unsigned short v[8];
#pragma unroll
        for (int j = 0; j < 8; ++j) {
            const float e = se[q * 8 + j + 32 * half][mm];
            unsigned short h1 = bf16_rne(e);
            v[j] = table ? bf16_rne(e - bf16_f(h1)) : h1;
        }
        *reinterpret_cast<uint4*>(ebf + (size_t)b * 2048 + table * 1024 +
                                  half * 512 + lane * 8) =
            *reinterpret_cast<const uint4*>(&v[0]);
    }

    if (b == 0 && tid == 0) { loss_acc[0] = 0.f; cnt[0] = 0; }
}

// Main: 256 blocks x 1024 threads, full ebf table in LDS (1 block/CU,
// 16 waves/CU), barrier-free MFMA K-loop, packed-u32 argmin, fused
// epilogue + loss. Per-row math identical to r13 (validated absmax 0).
__global__ __launch_bounds__(1024, 4) void vq_main(
    const float* __restrict__ x, const float* __restrict__ e2g,
    const unsigned short* __restrict__ ebf, const float* __restrict__ embT,
    float* __restrict__ out, float* __restrict__ loss_acc,
    int* __restrict__ slow, int* __restrict__ cnt) {
    const int tid = threadIdx.x;
    const int l = tid & 63;
    const int wv = tid >> 6;           // 0..15
    const int m = l & 15, q = l >> 4;

    __shared__ __align__(16) unsigned short sbf[65536];  // full 128KB table
    __shared__ float se2[512];
    __shared__ int bxl[RPB];
    __shared__ float wsum[16];

    // Issue x loads for A-fragments first (in flight under staging).
    float4 v0[2], v1[2], v2[2], v3[2];
#pragma unroll
    for (int rt = 0; rt < 2; ++rt) {
        const float* xr =
            x + ((size_t)blockIdx.x * RPB + wv * 32 + rt * 16 + m) * D + q * 8;
        v0[rt] = *reinterpret_cast<const float4*>(xr);
        v1[rt] = *reinterpret_cast<const float4*>(xr + 4);
        v2[rt] = *reinterpret_cast<const float4*>(xr + 32);
        v3[rt] = *reinterpret_cast<const float4*>(xr + 36);
    }

    // Stage the whole ebf table: 8192 uint4 / 1024 threads = 8 per thread,
    // fully coalesced; LDS writes contiguous b128 (2 lanes/bank = free).
    uint4 st[8];
#pragma unroll
    for (int i = 0; i < 8; ++i)
        st[i] = reinterpret_cast<const uint4*>(ebf)[i * 1024 + tid];
    if (tid < 128)
        reinterpret_cast<float4*>(se2)[tid] =
            reinterpret_cast<const float4*>(e2g)[tid];

    // A-fragments (bf16 hi/lo split; byte-identical chain to r10-r13).
    bf16x8 a10[2], a11[2], a20[2], a21[2];
#pragma unroll
    for (int rt = 0; rt < 2; ++rt) {
        float h0[8] = {v0[rt].x, v0[rt].y, v0[rt].z, v0[rt].w,
                       v1[rt].x, v1[rt].y, v1[rt].z, v1[rt].w};
        float h1f[8] = {v2[rt].x, v2[rt].y, v2[rt].z, v2[rt].w,
                        v3[rt].x, v3[rt].y, v3[rt].z, v3[rt].w};
        union { bf16x8 v; unsigned short u[8]; } u10, u11, u20, u21;
#pragma unroll
        for (int j = 0; j < 8; ++j) {
            unsigned short p = bf16_rne(h0[j]), r = bf16_rne(h1f[j]);
            u10.u[j] = p; u11.u[j] = r;
            u20.u[j] = bf16_rne(h0[j] - bf16_f(p));
            u21.u[j] = bf16_rne(h1f[j] - bf16_f(r));
        }
        a10[rt] = u10.v; a11[rt] = u11.v; a20[rt] = u20.v; a21[rt] = u21.v;
    }

#pragma unroll
    for (int i = 0; i < 8; ++i)
        reinterpret_cast<uint4*>(sbf)[i * 1024 + tid] = st[i];

    unsigned int m1p[2][4], m2p[2][4];
#pragma unroll
    for (int rt = 0; rt < 2; ++rt)
#pragma unroll
        for (int g = 0; g < 4; ++g) { m1p[rt][g] = 0xFFFFFFFFu; m2p[rt][g] = 0xFFFFFFFFu; }

    __syncthreads();  // table + e2 staged; the ONLY pre-epilogue barrier

    // Barrier-free K-loop: conflict-free ds_read_b128 b-frags + 12 MFMAs/t
    // (lo*lo dropped) + packed-u32 min update. Table is read-only.
#pragma unroll 2
    for (int t = 0; t < 32; ++t) {
        const unsigned short* tb = &sbf[t * 2048 + l * 8];
        bf16x8 b10 = *reinterpret_cast<const bf16x8*>(tb);
        bf16x8 b11 = *reinterpret_cast<const bf16x8*>(tb + 512);
        bf16x8 b20 = *reinterpret_cast<const bf16x8*>(tb + 1024);
        bf16x8 b21 = *reinterpret_cast<const bf16x8*>(tb + 1536);
        const float Bn = se2[t * 16 + m] + BIAS;
        f32x4 cp[2], cq[2];
#pragma unroll
        for (int rt = 0; rt < 2; ++rt) {
            cp[rt] = f32x4{0.f, 0.f, 0.f, 0.f};
            cq[rt] = f32x4{0.f, 0.f, 0.f, 0.f};
        }
#pragma unroll
        for (int rt = 0; rt < 2; ++rt) {
            cp[rt] = __builtin_amdgcn_mfma_f32_16x16x32_bf16(a10[rt], b10, cp[rt], 0, 0, 0);
            cq[rt] = __builtin_amdgcn_mfma_f32_16x16x32_bf16(a20[rt], b10, cq[rt], 0, 0, 0);
            cp[rt] = __builtin_amdgcn_mfma_f32_16x16x32_bf16(a11[rt], b11, cp[rt], 0, 0, 0);
            cq[rt] = __builtin_amdgcn_mfma_f32_16x16x32_bf16(a21[rt], b11, cq[rt], 0, 0, 0);
            cq[rt] = __builtin_amdgcn_mfma_f32_16x16x32_bf16(a10[rt], b20, cq[rt], 0, 0, 0);
            cq[rt] = __builtin_amdgcn_mfma_f32_16x16x32_bf16(a11[rt], b21, cq[rt], 0, 0, 0);
        }
#pragma unroll
        for (int rt = 0; rt < 2; ++rt)
#pragma unroll
            for (int g = 0; g < 4; ++g) {
                float s = fmaf(-2.f, cp[rt][g] + cq[rt][g], Bn);
                unsigned int pi =
                    (__float_as_uint(s) & 0xFFFFFFE0u) | (unsigned int)t;
                unsigned int o1 = m1p[rt][g];
                m2p[rt][g] = umin32(umax32(pi, o1), m2p[rt][g]);
                m1p[rt][g] = umin32(o1, pi);
            }
    }

    // Combine across the 16 lanes of each quad (r13-identical, u32).
#pragma unroll
    for (int rt = 0; rt < 2; ++rt)
#pragma unroll
        for (int g = 0; g < 4; ++g) {
            unsigned int uv = m1p[rt][g] & 0xFFFFFFE0u;
            int col = (int)((m1p[rt][g] & 31u) << 4) | m;
            unsigned int m2v = m2p[rt][g] & 0xFFFFFFE0u;
#pragma unroll
            for (int off = 1; off < 16; off <<= 1) {
                unsigned int ouv = (unsigned int)__shfl_xor((int)uv, off, 64);
                int ocol = __shfl_xor(col, off, 64);
                unsigned int om2 = (unsigned int)__shfl_xor((int)m2v, off, 64);
                unsigned int nm2 = umin32(umax32(uv, ouv), umin32(m2v, om2));
                bool take = (ouv < uv) || (ouv == uv && ocol < col);
                if (take) { uv = ouv; col = ocol; }
                m2v = nm2;  // equal mins, diff idx -> gap 0 -> slow
            }
            if (m == 0) {
                const int rl = wv * 32 + rt * 16 + q * 4 + g;  // row in block
                bxl[rl] = col;
                float gap = __uint_as_float(m2v) - __uint_as_float(uv);
                if (!(gap > THRESH_FAST)) {
                    int p = atomicAdd(cnt, 1);
                    if (p < SLOWCAP)
                        slow[p] = ((blockIdx.x * RPB + rl) << 9) | col;
                }
            }
        }
    __syncthreads();

    // Fused epilogue (r6-validated numerics, embT contiguous gather).
    float lsum = 0.f;
#pragma unroll
    for (int j = 0; j < 8; ++j) {
        const int e4 = j * 1024 + tid;
        const int rr2 = e4 >> 4;
        const int d0 = (e4 & 15) * 4;
        const size_t gbase = (size_t)(blockIdx.x * RPB + rr2) * D + d0;
        const float4 xv = *reinterpret_cast<const float4*>(x + gbase);
        const float4 qv =
            *reinterpret_cast<const float4*>(embT + bxl[rr2] * D + d0);
        float4 o;
        float t;
        t = __fsub_rn(qv.x, xv.x); lsum = __fmaf_rn(t, t, lsum);
        o.x = __fadd_rn(xv.x, t);
        t = __fsub_rn(qv.y, xv.y); lsum = __fmaf_rn(t, t, lsum);
        o.y = __fadd_rn(xv.y, t);
        t = __fsub_rn(qv.z, xv.z); lsum = __fmaf_rn(t, t, lsum);
        o.z = __fadd_rn(xv.z, t);
        t = __fsub_rn(qv.w, xv.w); lsum = __fmaf_rn(t, t, lsum);
        o.w = __fadd_rn(xv.w, t);
        *reinterpret_cast<float4*>(out + gbase) = o;
    }
#pragma unroll
    for (int off = 32; off > 0; off >>= 1) lsum += __shfl_down(lsum, off, 64);
    if (l == 0) wsum[wv] = lsum;
    __syncthreads();
    if (tid == 0) {
        float bs = wsum[0];
#pragma unroll
        for (int w = 1; w < 16; ++w) bs += wsum[w];
        atomicAdd(loss_acc, bs);
    }
}

// Fix: exact np rescan of flagged rows (r12 compute, best-total round —
// validated absmax 0). 4 rows/wave, x register-resident, distributed
// pairwise-8 A, shared ev slices, np-exact chains.
__global__ __launch_bounds__(256, 2) void vq_fix(const float* __restrict__ x,
                                                 const float* __restrict__ emb,
                                                 const float* __restrict__ embT,
                                                 const float* __restrict__ e2g,
                                                 const int* __restrict__ slow,
                                                 const int* __restrict__ cnt,
                                                 float* __restrict__ out,
                                                 float* __restrict__ loss_acc) {
    int n = cnt[0];
    if (n > SLOWCAP) n = SLOWCAP;
    const int lane = threadIdx.x & 63;
    const int wg = blockIdx.x * 4 + (threadIdx.x >> 6);  // 2048 waves
#pragma unroll 1
    for (int base = wg * 4; base < n; base += 2048 * 4) {
        const int c4 = (n - base < 4) ? (n - base) : 4;
        int rows[4], fidxs[4];
        float xr[4], A[4];
#pragma unroll
        for (int j = 0; j < 4; ++j) {
            const int src = base + ((j < c4) ? j : 0);  // pad with entry 0
            const int entry = __builtin_amdgcn_readfirstlane(slow[src]);
            rows[j] = entry >> 9;
            fidxs[j] = entry & 511;
            xr[j] = x[(size_t)rows[j] * D + lane];  // whole row in the wave
        }
        // A[j]: np pairwise-8 via distributed xor-tree (bit-exact grouping).
#pragma unroll
        for (int j = 0; j < 4; ++j) {
            const int jj = lane & 7;
            float v = __shfl(xr[j], jj, 64);
            float r8 = __fmul_rn(v, v);
#pragma unroll
            for (int ii = 8; ii < 64; ii += 8) {
                v = __shfl(xr[j], ii + jj, 64);
                r8 = __fadd_rn(r8, __fmul_rn(v, v));
            }
            r8 = __fadd_rn(r8, __shfl_xor(r8, 1, 64));
            r8 = __fadd_rn(r8, __shfl_xor(r8, 2, 64));
            r8 = __fadd_rn(r8, __shfl_xor(r8, 4, 64));
            A[j] = r8;
        }
        // Shared sim phase: one 2KB ev slice feeds 4 rows; xd via shuffle.
        float acc[4][8];
#pragma unroll
        for (int j = 0; j < 4; ++j)
#pragma unroll
            for (int u = 0; u < 8; ++u) acc[j][u] = 0.f;
#pragma unroll 4
        for (int d = 0; d < D; ++d) {
            float ev[8];
#pragma unroll
            for (int u = 0; u < 8; ++u) ev[u] = emb[d * K + lane + 64 * u];
#pragma unroll
            for (int j = 0; j < 4; ++j) {
                const float xd = __shfl(xr[j], d, 64);
#pragma unroll
                for (int u = 0; u < 8; ++u)
                    acc[j][u] = __fmaf_rn(xd, ev[u], acc[j][u]);
            }
        }
        float e2v[8];
#pragma unroll
        for (int u = 0; u < 8; ++u) e2v[u] = e2g[lane + 64 * u];
        // Per-row argmin + rewrite + loss delta (r9-identical chains).
#pragma unroll
        for (int j = 0; j < 4; ++j)
            if (j < c4) {
                const int row = rows[j];
                const int fidx = fidxs[j];
                float bv = 3.0e38f;
                int bi = 0;
#pragma unroll
                for (int u = 0; u < 8; ++u) {
                    const int c = lane + 64 * u;
                    float dv = __fsub_rn(__fadd_rn(A[j], e2v[u]),
                                         __fmul_rn(2.f, acc[j][u]));
                    if (dv < bv) { bv = dv; bi = c; }  // ascending c in lane
                }
#pragma unroll
                for (int off = 1; off < 64; off <<= 1) {
                    float ov = __shfl_xor(bv, off, 64);
                    int oi = __shfl_xor(bi, off, 64);
                    if (ov < bv || (ov == bv && oi < bi)) { bv = ov; bi = oi; }
                }
                float part = 0.f;
                if (lane < 16) {
                    const int d0 = lane * 4;
                    const float4 xv = *reinterpret_cast<const float4*>(
                        x + (size_t)row * D + d0);
                    const float4 qo = *reinterpret_cast<const float4*>(
                        embT + fidx * D + d0);
                    const float4 qn = *reinterpret_cast<const float4*>(
                        embT + bi * D + d0);
                    float so = 0.f, sn = 0.f, t;
                    float4 o;
                    t = __fsub_rn(qo.x, xv.x); so = __fmaf_rn(t, t, so);
                    t = __fsub_rn(qo.y, xv.y); so = __fmaf_rn(t, t, so);
                    t = __fsub_rn(qo.z, xv.z); so = __fmaf_rn(t, t, so);
                    t = __fsub_rn(qo.w, xv.w); so = __fmaf_rn(t, t, so);
                    t = __fsub_rn(qn.x, xv.x); sn = __fmaf_rn(t, t, sn);
                    o.x = __fadd_rn(xv.x, t);
                    t = __fsub_rn(qn.y, xv.y); sn = __fmaf_rn(t, t, sn);
                    o.y = __fadd_rn(xv.y, t);
                    t = __fsub_rn(qn.z, xv.z); sn = __fmaf_rn(t, t, sn);
                    o.z = __fadd_rn(xv.z, t);
                    t = __fsub_rn(qn.w, xv.w); sn = __fmaf_rn(t, t, sn);
                    o.w = __fadd_rn(xv.w, t);
                    *reinterpret_cast<float4*>(out + (size_t)row * D + d0) = o;
                    part = sn - so;  // exactly 0 when bi == fidx
                }
#pragma unroll
                for (int off = 32; off > 0; off >>= 1)
                    part += __shfl_down(part, off, 64);
                if (lane == 0 && part != 0.f) atomicAdd(loss_acc, part);
            }
    }
}

__global__ void vq_finalize(const float* __restrict__ loss_acc,
                            float* __restrict__ out_loss) {
    if (threadIdx.x == 0) {
        float mm = loss_acc[0] / (float)NELEM;  // /2^23: exact
        out_loss[0] = 1.25f * mm;               // == fl(0.25m + m)
    }
}

extern "C" void kernel_launch(void* const* d_in, const int* in_sizes, int n_in,
                              void* d_out, int out_size, void* d_ws, size_t ws_size,
                              hipStream_t stream) {
    const float* x = (const float*)d_in[0];
    const float* emb = (const float*)d_in[1];
    float* out = (float*)d_out;

    float* ws = (float*)d_ws;
    float* loss_acc = ws;
    int* cnt = (int*)ws + 1;
    float* e2 = ws + 64;
    unsigned short* ebf = (unsigned short*)(ws + 1024);  // 128 KB
    float* embT = ws + 33792;                            // 128 KB
    int* slow = (int*)(ws + 66560);                      // 64 KB

    vq_prep<<<32, 256, 0, stream>>>(emb, e2, ebf, embT, loss_acc, cnt);
    vq_main<<<NROWS / RPB, 1024, 0, stream>>>(x, e2, ebf, embT, out, loss_acc,
                                              slow, cnt);
    vq_fix<<<512, 256, 0, stream>>>(x, emb, embT, e2, slow, cnt, out, loss_acc);
    vq_finalize<<<1, 64, 0, stream>>>(loss_acc, out + NELEM);
}